// Round 12
// baseline (171.244 us; speedup 1.0000x reference)
//
#include <hip/hip_runtime.h>
#include <hip/hip_bf16.h>

// B=4, H=W=56, C=256, 7x7 windows of 8x8, 8 heads x 32, top-4.
// Inputs fp32; d_out fp32. Intermediates bf16; MFMA bf16 w/ fp32 accum.
// 5-launch pipeline: prep -> [qkv_gemm | route] -> lepe -> attn(+add) -> proj
#define NPIX 12544   // B*56*56

typedef short bf16x8 __attribute__((ext_vector_type(8)));
typedef float f32x4  __attribute__((ext_vector_type(4)));

__device__ __forceinline__ float bf2f(unsigned short u) {
    unsigned int x = ((unsigned int)u) << 16;
    float f; __builtin_memcpy(&f, &x, sizeof(f)); return f;
}
__device__ __forceinline__ unsigned short f2bf(float f) {
    __hip_bfloat16 h = __float2bfloat16(f);
    unsigned short u; __builtin_memcpy(&u, &h, 2); return u;
}
// async global->LDS DMA, 16B per lane; LDS dest is wave-uniform base + lane*16
__device__ __forceinline__ void load_lds16(const unsigned short* g, unsigned short* l) {
    __builtin_amdgcn_global_load_lds(
        (const __attribute__((address_space(1))) unsigned int*)g,
        (__attribute__((address_space(3))) unsigned int*)l,
        16, 0, 0);
}

// ---------------------------------------------------------------------------
// K0: fused prep.
//   blocks 0..391   : x -> bf16 + per-window mean (2 blocks/window, 128 ch each)
//   blocks 392..439 : Wqkv^T tiles (64x64 LDS transpose); Wk tiles also emit
//                     fp32 WkT[j][c] = Wk[c][j] for the coalesced route path
//   blocks 440..455 : Wo^T tiles
// ---------------------------------------------------------------------------
__global__ __launch_bounds__(256) void k_prep(
    const float* __restrict__ X, unsigned short* __restrict__ Xb,
    float* __restrict__ xmean,
    const float* __restrict__ Wqkv, const float* __restrict__ Wo,
    unsigned short* __restrict__ Wtq, unsigned short* __restrict__ Wto,
    float* __restrict__ WkT)
{
    __shared__ __align__(16) unsigned char sm[64 * 65 * 4];   // 16.6 KB union
    const int t = threadIdx.x;
    const int blk = blockIdx.x;
    if (blk < 392) {
        float* part = (float*)sm;                 // [8 ps][32 cg][4]
        const int w = blk >> 1, hc = blk & 1;
        const int b = w / 49, p = w % 49;
        const int wi = p / 7, wj = p % 7;
        const int ch0 = hc * 128;
        const int ps = t >> 5, cg = t & 31;
        float4 s = {0.f, 0.f, 0.f, 0.f};
        #pragma unroll
        for (int i = 0; i < 8; i++) {
            int pp = ps * 8 + i;
            int y = wi * 8 + (pp >> 3), x = wj * 8 + (pp & 7);
            int idx = (((b * 56) + y) * 56 + x) * 256 + ch0 + cg * 4;
            float4 v = *reinterpret_cast<const float4*>(X + idx);
            s.x += v.x; s.y += v.y; s.z += v.z; s.w += v.w;
            ushort4 o = { f2bf(v.x), f2bf(v.y), f2bf(v.z), f2bf(v.w) };
            *reinterpret_cast<ushort4*>(Xb + idx) = o;
        }
        *reinterpret_cast<float4*>(part + t * 4) = *reinterpret_cast<float4*>(&s);
        __syncthreads();
        if (t < 32) {
            float4 m = {0.f, 0.f, 0.f, 0.f};
            #pragma unroll
            for (int ps2 = 0; ps2 < 8; ps2++) {
                float4 v = *reinterpret_cast<float4*>(part + (ps2 * 32 + t) * 4);
                m.x += v.x; m.y += v.y; m.z += v.z; m.w += v.w;
            }
            m.x *= (1.f / 64.f); m.y *= (1.f / 64.f);
            m.z *= (1.f / 64.f); m.w *= (1.f / 64.f);
            *reinterpret_cast<float4*>(xmean + w * 256 + ch0 + t * 4) = m;
        }
    } else {
        float* tile = (float*)sm;                 // [64][65]
        int tb = blk - 392;
        const float* Wsrc; unsigned short* Wdst; int N, kt, nt;
        if (tb < 48) { Wsrc = Wqkv; Wdst = Wtq; N = 768; kt = tb / 12; nt = tb % 12; }
        else { tb -= 48; Wsrc = Wo; Wdst = Wto; N = 256; kt = tb / 4; nt = tb % 4; }
        const int k0 = kt * 64, n0 = nt * 64;
        const int r0 = t >> 6, c = t & 63;
        #pragma unroll
        for (int i = 0; i < 16; i++) {
            int r = i * 4 + r0;
            tile[r * 65 + c] = Wsrc[(size_t)(k0 + r) * N + n0 + c];
        }
        __syncthreads();
        const bool isWk = (N == 768) && (n0 >= 256) && (n0 < 512);
        #pragma unroll
        for (int i = 0; i < 16; i++) {
            int n = i * 4 + r0;
            float v = tile[c * 65 + n];
            Wdst[(size_t)(n0 + n) * 256 + k0 + c] = f2bf(v);
            if (isWk) WkT[(size_t)(n0 + n - 256) * 256 + k0 + c] = v;
        }
    }
}

// ---------------------------------------------------------------------------
// K1: merged launch — qkv GEMM (blocks 0..587) | route (blocks 588..783)
//   Route: logit[p][q] ∝ xmean[q]·u, u = Wk^T·(xmean[p]@Wq + bq), fp32,
//   coalesced via WkT. q-independent terms dropped (top-k order-invariant).
// ---------------------------------------------------------------------------
__global__ __launch_bounds__(256) void k_main1(
    const unsigned short* __restrict__ A,   // xb [12544][256]
    const unsigned short* __restrict__ Bt,  // Wtq [768][256]
    const float* __restrict__ bias,         // bqkv [768]
    unsigned short* __restrict__ O,         // qkv bf16
    const float* __restrict__ xmean,        // [196][256]
    const float* __restrict__ Wqkv,         // fp32 [256][768]
    const float* __restrict__ WkT,          // fp32 [256][256]
    int* __restrict__ ridx)
{
    __shared__ __align__(16) unsigned char sm1[16384];
    const int t = threadIdx.x;
    const int blk = blockIdx.x;
    if (blk < 588) {
        unsigned short* As = (unsigned short*)sm1;          // [128*32]
        unsigned short* Bs = (unsigned short*)(sm1 + 8192); // [128*32]
        const int m0 = (blk % 98) * 128, n0 = (blk / 98) * 128;
        const int wave = t >> 6, lane = t & 63, quad = lane >> 4, lo = lane & 15;
        const int wm = wave & 1, wn = wave >> 1;
        const int sr = wave * 16 + (lane >> 2);
        const int sc = lane & 3;
        f32x4 acc[4][4];
        #pragma unroll
        for (int i = 0; i < 4; i++)
            #pragma unroll
            for (int j = 0; j < 4; j++) acc[i][j] = (f32x4){0.f, 0.f, 0.f, 0.f};

        for (int kt = 0; kt < 256; kt += 32) {
            __syncthreads();
            #pragma unroll
            for (int j = 0; j < 2; j++) {
                int row = j * 64 + sr;
                int e = sc ^ ((row >> 1) & 3);
                load_lds16(A  + (size_t)(m0 + row) * 256 + kt + e * 8, &As[row * 32 + sc * 8]);
                load_lds16(Bt + (size_t)(n0 + row) * 256 + kt + e * 8, &Bs[row * 32 + sc * 8]);
            }
            __syncthreads();
            bf16x8 af[4], bfr[4];
            #pragma unroll
            for (int mt = 0; mt < 4; mt++) {
                int row = wm * 64 + mt * 16 + lo;
                int c = quad ^ ((row >> 1) & 3);
                af[mt] = *reinterpret_cast<const bf16x8*>(&As[row * 32 + c * 8]);
            }
            #pragma unroll
            for (int nt = 0; nt < 4; nt++) {
                int col = wn * 64 + nt * 16 + lo;
                int c = quad ^ ((col >> 1) & 3);
                bfr[nt] = *reinterpret_cast<const bf16x8*>(&Bs[col * 32 + c * 8]);
            }
            #pragma unroll
            for (int mt = 0; mt < 4; mt++)
                #pragma unroll
                for (int nt = 0; nt < 4; nt++)
                    acc[mt][nt] = __builtin_amdgcn_mfma_f32_16x16x32_bf16(
                        af[mt], bfr[nt], acc[mt][nt], 0, 0, 0);
        }
        float bv[4];
        #pragma unroll
        for (int nt = 0; nt < 4; nt++) bv[nt] = bias[n0 + wn * 64 + nt * 16 + lo];
        #pragma unroll
        for (int mt = 0; mt < 4; mt++)
            #pragma unroll
            for (int nt = 0; nt < 4; nt++) {
                int n = n0 + wn * 64 + nt * 16 + lo;
                #pragma unroll
                for (int r = 0; r < 4; r++) {
                    int m = m0 + wm * 64 + mt * 16 + quad * 4 + r;
                    O[m * 768 + n] = f2bf(acc[mt][nt][r] + bv[nt]);
                }
            }
    } else {
        float* xq   = (float*)sm1;                 // [256]
        float* qs   = (float*)(sm1 + 1024);        // [256]
        float* us   = (float*)(sm1 + 2048);        // [256]
        float* part = (float*)(sm1 + 3072);        // [49][4]
        float* lg   = (float*)(sm1 + 3072 + 784);  // [49]
        const int u = blk - 588;                   // 0..195 = b*49 + p
        const int b = u / 49;
        xq[t] = xmean[(size_t)u * 256 + t];
        __syncthreads();
        {   // qwin[p][t] (fp32 exact, includes q-bias); coalesced
            float a = 0.f;
            for (int k = 0; k < 256; k++) a += xq[k] * Wqkv[k * 768 + t];
            qs[t] = a + bias[t];
        }
        __syncthreads();
        {   // u[t] = sum_j qs[j] * WkT[j][t]; coalesced
            float a = 0.f;
            for (int j = 0; j < 256; j++) a += qs[j] * WkT[j * 256 + t];
            us[t] = a;
        }
        __syncthreads();
        if (t < 196) {   // lg[d] = xmean[b,d] · u  (4 partial lanes per d)
            int d = t >> 2, pr = t & 3;
            const float* xm = xmean + (size_t)(b * 49 + d) * 256 + pr * 64;
            float a = 0.f;
            for (int k = 0; k < 64; k++) a += xm[k] * us[pr * 64 + k];
            part[d * 4 + pr] = a;
        }
        __syncthreads();
        if (t < 49) lg[t] = part[t * 4] + part[t * 4 + 1] + part[t * 4 + 2] + part[t * 4 + 3];
        __syncthreads();
        if (t == 0) {
            unsigned long long used = 0ull;
            for (int sel = 0; sel < 4; sel++) {
                float best = -1e30f; int bi = 0;
                for (int qq = 0; qq < 49; qq++)
                    if (!((used >> qq) & 1ull) && lg[qq] > best) { best = lg[qq]; bi = qq; }
                used |= (1ull << bi);
                ridx[u * 4 + sel] = bi;
            }
        }
    }
}

// ---------------------------------------------------------------------------
// K2: depthwise 5x5 LEPE conv on v channels -> bf16  (standalone, 25.6 KB LDS
//     => 6 blocks/CU; measured-good form from round 5)
// ---------------------------------------------------------------------------
__global__ __launch_bounds__(256) void k_lepe(
    const unsigned short* __restrict__ QKV,
    const float* __restrict__ lw, const float* __restrict__ lb,
    unsigned short* __restrict__ Olepe)
{
    __shared__ float lws[25 * 256];
    const int t = threadIdx.x;
    #pragma unroll
    for (int i = 0; i < 25; i++) lws[i * 256 + t] = lw[i * 256 + t];

    const int pl = t & 7;
    const int cg = t >> 3;
    const int c0 = cg * 8;
    const int gid = blockIdx.x * 8 + pl;
    const int b = gid / 3136, rem = gid % 3136;
    const int y = rem / 56, x = rem % 56;
    __syncthreads();

    float acc[8];
    {
        float4 b0 = *reinterpret_cast<const float4*>(lb + c0);
        float4 b1 = *reinterpret_cast<const float4*>(lb + c0 + 4);
        acc[0] = b0.x; acc[1] = b0.y; acc[2] = b0.z; acc[3] = b0.w;
        acc[4] = b1.x; acc[5] = b1.y; acc[6] = b1.z; acc[7] = b1.w;
    }
    #pragma unroll
    for (int ky = 0; ky < 5; ky++) {
        int yy = y + ky - 2;
        if (yy < 0 || yy >= 56) continue;
        #pragma unroll
        for (int kx = 0; kx < 5; kx++) {
            int xx = x + kx - 2;
            if (xx < 0 || xx >= 56) continue;
            bf16x8 v = *reinterpret_cast<const bf16x8*>(
                QKV + (((b * 56) + yy) * 56 + xx) * 768 + 512 + c0);
            const float* wrow = &lws[(ky * 5 + kx) * 256 + c0];
            float4 w0 = *reinterpret_cast<const float4*>(wrow);
            float4 w1 = *reinterpret_cast<const float4*>(wrow + 4);
            acc[0] += bf2f((unsigned short)v[0]) * w0.x;
            acc[1] += bf2f((unsigned short)v[1]) * w0.y;
            acc[2] += bf2f((unsigned short)v[2]) * w0.z;
            acc[3] += bf2f((unsigned short)v[3]) * w0.w;
            acc[4] += bf2f((unsigned short)v[4]) * w1.x;
            acc[5] += bf2f((unsigned short)v[5]) * w1.y;
            acc[6] += bf2f((unsigned short)v[6]) * w1.z;
            acc[7] += bf2f((unsigned short)v[7]) * w1.w;
        }
    }
    bf16x8 o;
    #pragma unroll
    for (int j = 0; j < 8; j++) o[j] = (short)f2bf(acc[j]);
    *reinterpret_cast<bf16x8*>(Olepe + (size_t)gid * 256 + c0) = o;
}

// ---------------------------------------------------------------------------
// K3: MFMA gathered window attention + "+lepe" add epilogue -> Osum
//     (round-8 validated form)
// ---------------------------------------------------------------------------
__global__ __launch_bounds__(256) void k_attn(
    const unsigned short* __restrict__ QKV,
    const int* __restrict__ ridx,
    const unsigned short* __restrict__ Olepe,
    unsigned short* __restrict__ Osum)
{
    __shared__ __align__(16) unsigned char smem[50688];
    unsigned short* Vt = (unsigned short*)smem;                  // [32][264]
    unsigned short* Qs = (unsigned short*)(smem + 16896);        // [64][40]
    unsigned short* Ks = (unsigned short*)(smem + 22016);        // [256][40]
    unsigned short* Ps = (unsigned short*)(smem + 16896);        // 4 x [16][264]

    const int p = blockIdx.x, head = blockIdx.y, b = blockIdx.z;
    const int t = threadIdx.x;
    const int wi = p / 7, wj = p % 7;
    const int wave = t >> 6, lane = t & 63, quad = lane >> 4, lo = lane & 15;
    const int pix4 = t >> 2, c4 = t & 3;

    {
        int y = wi * 8 + (pix4 >> 3), x = wj * 8 + (pix4 & 7);
        const unsigned short* qp = QKV + (((b * 56) + y) * 56 + x) * 768 + head * 32 + c4 * 8;
        bf16x8 v = *reinterpret_cast<const bf16x8*>(qp);
        int sw = c4 ^ ((pix4 >> 3) & 3);
        *reinterpret_cast<bf16x8*>(&Qs[pix4 * 40 + sw * 8]) = v;
    }
    #pragma unroll
    for (int pass = 0; pass < 4; pass++) {
        int sel = ridx[(b * 49 + p) * 4 + pass];
        int si = sel / 7, sj = sel % 7;
        int y = si * 8 + (pix4 >> 3), x = sj * 8 + (pix4 & 7);
        const unsigned short* base = QKV + (((b * 56) + y) * 56 + x) * 768 + 256 + head * 32;
        bf16x8 kv = *reinterpret_cast<const bf16x8*>(base + c4 * 8);
        bf16x8 vv = *reinterpret_cast<const bf16x8*>(base + 256 + c4 * 8);
        int krow = pass * 64 + pix4;
        int sw = c4 ^ ((krow >> 3) & 3);
        *reinterpret_cast<bf16x8*>(&Ks[krow * 40 + sw * 8]) = kv;
        #pragma unroll
        for (int j = 0; j < 8; j++)
            Vt[(c4 * 8 + j) * 264 + krow] = (unsigned short)vv[j];
    }
    __syncthreads();

    f32x4 sc[16];
    {
        int row = wave * 16 + lo;
        bf16x8 af = *reinterpret_cast<const bf16x8*>(
            &Qs[row * 40 + ((quad ^ ((row >> 3) & 3)) * 8)]);
        f32x4 z = (f32x4){0.f, 0.f, 0.f, 0.f};
        #pragma unroll
        for (int nt = 0; nt < 16; nt++) {
            int key = nt * 16 + lo;
            bf16x8 bfr = *reinterpret_cast<const bf16x8*>(
                &Ks[key * 40 + ((quad ^ ((key >> 3) & 3)) * 8)]);
            sc[nt] = __builtin_amdgcn_mfma_f32_16x16x32_bf16(af, bfr, z, 0, 0, 0);
        }
    }
    float M[4] = {-1e30f, -1e30f, -1e30f, -1e30f};
    #pragma unroll
    for (int nt = 0; nt < 16; nt++)
        #pragma unroll
        for (int r = 0; r < 4; r++) M[r] = fmaxf(M[r], sc[nt][r] * 0.0625f);
    #pragma unroll
    for (int d = 1; d < 16; d <<= 1)
        #pragma unroll
        for (int r = 0; r < 4; r++) M[r] = fmaxf(M[r], __shfl_xor(M[r], d));
    float l[4] = {0.f, 0.f, 0.f, 0.f};
    #pragma unroll
    for (int nt = 0; nt < 16; nt++)
        #pragma unroll
        for (int r = 0; r < 4; r++) {
            float e = __expf(sc[nt][r] * 0.0625f - M[r]);
            sc[nt][r] = e;
            l[r] += e;
        }
    #pragma unroll
    for (int d = 1; d < 16; d <<= 1)
        #pragma unroll
        for (int r = 0; r < 4; r++) l[r] += __shfl_xor(l[r], d);

    __syncthreads();   // all waves done reading Qs/Ks -> Ps may overwrite

    unsigned short* myPs = Ps + wave * 16 * 264;
    #pragma unroll
    for (int nt = 0; nt < 16; nt++)
        #pragma unroll
        for (int r = 0; r < 4; r++)
            myPs[(quad * 4 + r) * 264 + nt * 16 + lo] = f2bf(sc[nt][r]);
    // (no barrier: PV reads only this wave's own Ps tile)

    f32x4 o0 = (f32x4){0.f, 0.f, 0.f, 0.f}, o1 = o0;
    #pragma unroll
    for (int kt = 0; kt < 8; kt++) {
        bf16x8 pa = *reinterpret_cast<const bf16x8*>(
            &myPs[lo * 264 + kt * 32 + quad * 8]);
        bf16x8 vb0 = *reinterpret_cast<const bf16x8*>(
            &Vt[lo * 264 + kt * 32 + quad * 8]);
        bf16x8 vb1 = *reinterpret_cast<const bf16x8*>(
            &Vt[(16 + lo) * 264 + kt * 32 + quad * 8]);
        o0 = __builtin_amdgcn_mfma_f32_16x16x32_bf16(pa, vb0, o0, 0, 0, 0);
        o1 = __builtin_amdgcn_mfma_f32_16x16x32_bf16(pa, vb1, o1, 0, 0, 0);
    }
    #pragma unroll
    for (int r = 0; r < 4; r++) {
        int q = wave * 16 + quad * 4 + r;
        int y = wi * 8 + (q >> 3), x = wj * 8 + (q & 7);
        size_t base = (size_t)(((b * 56) + y) * 56 + x) * 256 + head * 32;
        const unsigned short* lp = Olepe + base;
        unsigned short* op = Osum + base;
        float inv = 1.0f / l[r];
        op[lo]      = f2bf(o0[r] * inv + bf2f(lp[lo]));
        op[16 + lo] = f2bf(o1[r] * inv + bf2f(lp[16 + lo]));
    }
}

// ---------------------------------------------------------------------------
// K4: out proj (MFMA): Osum[12544,256] @ Wo[256,256] + bo -> fp32 out
//     (round-8 validated single-operand form)
// ---------------------------------------------------------------------------
__global__ __launch_bounds__(256) void k_proj(
    const unsigned short* __restrict__ A,
    const unsigned short* __restrict__ Bt,   // Wto [256][256]
    const float* __restrict__ bias,
    float* __restrict__ O)
{
    __shared__ unsigned short As[128 * 32];
    __shared__ unsigned short Bs[64 * 32];
    const int t = threadIdx.x;
    const int m0 = blockIdx.x * 128, n0 = blockIdx.y * 64;
    const int wave = t >> 6, lane = t & 63, quad = lane >> 4, lo = lane & 15;
    const int sr = wave * 16 + (lane >> 2);
    const int sc = lane & 3;
    f32x4 acc[2][4];
    #pragma unroll
    for (int i = 0; i < 2; i++)
        #pragma unroll
        for (int j = 0; j < 4; j++) acc[i][j] = (f32x4){0.f, 0.f, 0.f, 0.f};

    for (int kt = 0; kt < 256; kt += 32) {
        __syncthreads();
        #pragma unroll
        for (int j = 0; j < 2; j++) {
            int row = j * 64 + sr;
            int e = sc ^ ((row >> 1) & 3);
            load_lds16(A + (size_t)(m0 + row) * 256 + kt + e * 8, &As[row * 32 + sc * 8]);
        }
        {
            int e = sc ^ ((sr >> 1) & 3);
            load_lds16(Bt + (size_t)(n0 + sr) * 256 + kt + e * 8, &Bs[sr * 32 + sc * 8]);
        }
        __syncthreads();
        bf16x8 af[2], bfr[4];
        #pragma unroll
        for (int mt = 0; mt < 2; mt++) {
            int row = wave * 32 + mt * 16 + lo;
            int c = quad ^ ((row >> 1) & 3);
            af[mt] = *reinterpret_cast<const bf16x8*>(&As[row * 32 + c * 8]);
        }
        #pragma unroll
        for (int nt = 0; nt < 4; nt++) {
            int col = nt * 16 + lo;
            int c = quad ^ ((col >> 1) & 3);
            bfr[nt] = *reinterpret_cast<const bf16x8*>(&Bs[col * 32 + c * 8]);
        }
        #pragma unroll
        for (int mt = 0; mt < 2; mt++)
            #pragma unroll
            for (int nt = 0; nt < 4; nt++)
                acc[mt][nt] = __builtin_amdgcn_mfma_f32_16x16x32_bf16(
                    af[mt], bfr[nt], acc[mt][nt], 0, 0, 0);
    }
    float bv[4];
    #pragma unroll
    for (int nt = 0; nt < 4; nt++) bv[nt] = bias[n0 + nt * 16 + lo];
    #pragma unroll
    for (int mt = 0; mt < 2; mt++)
        #pragma unroll
        for (int nt = 0; nt < 4; nt++) {
            int n = n0 + nt * 16 + lo;
            #pragma unroll
            for (int r = 0; r < 4; r++) {
                int m = m0 + wave * 32 + mt * 16 + quad * 4 + r;
                O[m * 256 + n] = acc[mt][nt][r] + bv[nt];
            }
        }
}

// ---------------------------------------------------------------------------
extern "C" void kernel_launch(void* const* d_in, const int* in_sizes, int n_in,
                              void* d_out, int out_size, void* d_ws, size_t ws_size,
                              hipStream_t stream)
{
    const float* x    = (const float*)d_in[0];
    const float* Wqkv = (const float*)d_in[1];
    const float* bqkv = (const float*)d_in[2];
    const float* Wo   = (const float*)d_in[3];
    const float* bo   = (const float*)d_in[4];
    const float* lw   = (const float*)d_in[5];
    const float* lb   = (const float*)d_in[6];
    float* out = (float*)d_out;

    char* ws = (char*)d_ws;
    size_t off = 0;
    unsigned short* qkv   = (unsigned short*)(ws + off); off += (size_t)NPIX * 768 * 2;
    unsigned short* xb    = (unsigned short*)(ws + off); off += (size_t)NPIX * 256 * 2;
    unsigned short* Wtq   = (unsigned short*)(ws + off); off += 768 * 256 * 2;
    unsigned short* Wto   = (unsigned short*)(ws + off); off += 256 * 256 * 2;
    unsigned short* Osum  = (unsigned short*)(ws + off); off += (size_t)NPIX * 256 * 2;
    unsigned short* Olepe = (unsigned short*)(ws + off); off += (size_t)NPIX * 256 * 2;
    float* WkT   = (float*)(ws + off); off += 256 * 256 * 4;
    float* xmean = (float*)(ws + off); off += 196 * 256 * 4;
    int*   ridx  = (int*)(ws + off);   off += 196 * 4 * 4;

    k_prep <<<dim3(456),      256, 0, stream>>>(x, xb, xmean, Wqkv, Wo, Wtq, Wto, WkT);
    k_main1<<<dim3(784),      256, 0, stream>>>(xb, Wtq, bqkv, qkv, xmean, Wqkv, WkT, ridx);
    k_lepe <<<dim3(1568),     256, 0, stream>>>(qkv, lw, lb, Olepe);
    k_attn <<<dim3(49, 8, 4), 256, 0, stream>>>(qkv, ridx, Olepe, Osum);
    k_proj <<<dim3(98, 4),    256, 0, stream>>>(Osum, Wto, bo, out);
}

// Round 13
// 155.631 us; speedup vs baseline: 1.1003x; 1.1003x over previous
//
#include <hip/hip_runtime.h>
#include <hip/hip_bf16.h>

// B=4, H=W=56, C=256, 7x7 windows of 8x8, 8 heads x 32, top-4.
// Inputs fp32; d_out fp32. Intermediates bf16; MFMA bf16 w/ fp32 accum.
// R8 pipeline: prep -> [qkv_gemm | winproj] -> [route | lepe] -> attn(+add) -> proj
// R13 change: k_attn LDS 50.7KB -> 37.4KB (4 blocks/CU) via DMA staging + split-P.
#define NPIX 12544   // B*56*56

typedef short bf16x8 __attribute__((ext_vector_type(8)));
typedef float f32x4  __attribute__((ext_vector_type(4)));

__device__ __forceinline__ float bf2f(unsigned short u) {
    unsigned int x = ((unsigned int)u) << 16;
    float f; __builtin_memcpy(&f, &x, sizeof(f)); return f;
}
__device__ __forceinline__ unsigned short f2bf(float f) {
    __hip_bfloat16 h = __float2bfloat16(f);
    unsigned short u; __builtin_memcpy(&u, &h, 2); return u;
}
// async global->LDS DMA, 16B per lane; LDS dest is wave-uniform base + lane*16
__device__ __forceinline__ void load_lds16(const unsigned short* g, unsigned short* l) {
    __builtin_amdgcn_global_load_lds(
        (const __attribute__((address_space(1))) unsigned int*)g,
        (__attribute__((address_space(3))) unsigned int*)l,
        16, 0, 0);
}

// ---------------------------------------------------------------------------
// K0: fused prep (R8 form).
//   blocks 0..391   : x -> bf16 + per-window mean (2 blocks/window, 128 ch each)
//   blocks 392..439 : Wqkv^T tiles (64x64 LDS transpose)
//   blocks 440..455 : Wo^T tiles
// ---------------------------------------------------------------------------
__global__ __launch_bounds__(256) void k_prep(
    const float* __restrict__ X, unsigned short* __restrict__ Xb,
    float* __restrict__ xmean,
    const float* __restrict__ Wqkv, const float* __restrict__ Wo,
    unsigned short* __restrict__ Wtq, unsigned short* __restrict__ Wto)
{
    __shared__ __align__(16) unsigned char sm[64 * 65 * 4];   // 16.6 KB union
    const int t = threadIdx.x;
    const int blk = blockIdx.x;
    if (blk < 392) {
        float* part = (float*)sm;                 // [8 ps][32 cg][4]
        const int w = blk >> 1, hc = blk & 1;
        const int b = w / 49, p = w % 49;
        const int wi = p / 7, wj = p % 7;
        const int ch0 = hc * 128;
        const int ps = t >> 5, cg = t & 31;
        float4 s = {0.f, 0.f, 0.f, 0.f};
        #pragma unroll
        for (int i = 0; i < 8; i++) {
            int pp = ps * 8 + i;
            int y = wi * 8 + (pp >> 3), x = wj * 8 + (pp & 7);
            int idx = (((b * 56) + y) * 56 + x) * 256 + ch0 + cg * 4;
            float4 v = *reinterpret_cast<const float4*>(X + idx);
            s.x += v.x; s.y += v.y; s.z += v.z; s.w += v.w;
            ushort4 o = { f2bf(v.x), f2bf(v.y), f2bf(v.z), f2bf(v.w) };
            *reinterpret_cast<ushort4*>(Xb + idx) = o;
        }
        *reinterpret_cast<float4*>(part + t * 4) = *reinterpret_cast<float4*>(&s);
        __syncthreads();
        if (t < 32) {
            float4 m = {0.f, 0.f, 0.f, 0.f};
            #pragma unroll
            for (int ps2 = 0; ps2 < 8; ps2++) {
                float4 v = *reinterpret_cast<float4*>(part + (ps2 * 32 + t) * 4);
                m.x += v.x; m.y += v.y; m.z += v.z; m.w += v.w;
            }
            m.x *= (1.f / 64.f); m.y *= (1.f / 64.f);
            m.z *= (1.f / 64.f); m.w *= (1.f / 64.f);
            *reinterpret_cast<float4*>(xmean + w * 256 + ch0 + t * 4) = m;
        }
    } else {
        float* tile = (float*)sm;                 // [64][65]
        int tb = blk - 392;
        const float* Wsrc; unsigned short* Wdst; int N, kt, nt;
        if (tb < 48) { Wsrc = Wqkv; Wdst = Wtq; N = 768; kt = tb / 12; nt = tb % 12; }
        else { tb -= 48; Wsrc = Wo; Wdst = Wto; N = 256; kt = tb / 4; nt = tb % 4; }
        const int k0 = kt * 64, n0 = nt * 64;
        const int r0 = t >> 6, c = t & 63;
        #pragma unroll
        for (int i = 0; i < 16; i++) {
            int r = i * 4 + r0;
            tile[r * 65 + c] = Wsrc[(size_t)(k0 + r) * N + n0 + c];
        }
        __syncthreads();
        #pragma unroll
        for (int i = 0; i < 16; i++) {
            int n = i * 4 + r0;
            Wdst[(size_t)(n0 + n) * 256 + k0 + c] = f2bf(tile[c * 65 + n]);
        }
    }
}

// ---------------------------------------------------------------------------
// K1: merged launch — qkv GEMM (blocks 0..587) | winproj (blocks 588..979)  [R8]
// ---------------------------------------------------------------------------
__global__ __launch_bounds__(256) void k_main1(
    const unsigned short* __restrict__ A,   // xb [12544][256]
    const unsigned short* __restrict__ Bt,  // Wtq [768][256]
    const float* __restrict__ bias,         // bqkv [768]
    unsigned short* __restrict__ O,         // qkv bf16
    const float* __restrict__ xmean,
    const float* __restrict__ Wqkv,         // fp32 [256][768]
    float* __restrict__ qwin, float* __restrict__ kwin)
{
    __shared__ __align__(16) unsigned char sm1[16384];
    const int t = threadIdx.x;
    const int blk = blockIdx.x;
    if (blk < 588) {
        unsigned short* As = (unsigned short*)sm1;          // [128*32]
        unsigned short* Bs = (unsigned short*)(sm1 + 8192); // [128*32]
        const int m0 = (blk % 98) * 128, n0 = (blk / 98) * 128;
        const int wave = t >> 6, lane = t & 63, quad = lane >> 4, lo = lane & 15;
        const int wm = wave & 1, wn = wave >> 1;
        const int sr = wave * 16 + (lane >> 2);
        const int sc = lane & 3;
        f32x4 acc[4][4];
        #pragma unroll
        for (int i = 0; i < 4; i++)
            #pragma unroll
            for (int j = 0; j < 4; j++) acc[i][j] = (f32x4){0.f, 0.f, 0.f, 0.f};

        for (int kt = 0; kt < 256; kt += 32) {
            __syncthreads();
            #pragma unroll
            for (int j = 0; j < 2; j++) {
                int row = j * 64 + sr;
                int e = sc ^ ((row >> 1) & 3);
                load_lds16(A  + (size_t)(m0 + row) * 256 + kt + e * 8, &As[row * 32 + sc * 8]);
                load_lds16(Bt + (size_t)(n0 + row) * 256 + kt + e * 8, &Bs[row * 32 + sc * 8]);
            }
            __syncthreads();
            bf16x8 af[4], bfr[4];
            #pragma unroll
            for (int mt = 0; mt < 4; mt++) {
                int row = wm * 64 + mt * 16 + lo;
                int c = quad ^ ((row >> 1) & 3);
                af[mt] = *reinterpret_cast<const bf16x8*>(&As[row * 32 + c * 8]);
            }
            #pragma unroll
            for (int nt = 0; nt < 4; nt++) {
                int col = wn * 64 + nt * 16 + lo;
                int c = quad ^ ((col >> 1) & 3);
                bfr[nt] = *reinterpret_cast<const bf16x8*>(&Bs[col * 32 + c * 8]);
            }
            #pragma unroll
            for (int mt = 0; mt < 4; mt++)
                #pragma unroll
                for (int nt = 0; nt < 4; nt++)
                    acc[mt][nt] = __builtin_amdgcn_mfma_f32_16x16x32_bf16(
                        af[mt], bfr[nt], acc[mt][nt], 0, 0, 0);
        }
        float bv[4];
        #pragma unroll
        for (int nt = 0; nt < 4; nt++) bv[nt] = bias[n0 + wn * 64 + nt * 16 + lo];
        #pragma unroll
        for (int mt = 0; mt < 4; mt++)
            #pragma unroll
            for (int nt = 0; nt < 4; nt++) {
                int n = n0 + wn * 64 + nt * 16 + lo;
                #pragma unroll
                for (int r = 0; r < 4; r++) {
                    int m = m0 + wm * 64 + mt * 16 + quad * 4 + r;
                    O[m * 768 + n] = f2bf(acc[mt][nt][r] + bv[nt]);
                }
            }
    } else {
        float* xs = (float*)sm1;                  // [256]
        const int u = blk - 588;
        const int bp = u % 196;
        const int half = u / 196;                 // 0 -> qwin, 1 -> kwin
        const int c = t;
        xs[c] = xmean[bp * 256 + c];
        __syncthreads();
        const int col = half * 256 + c;
        float a = 0.f;
        for (int k = 0; k < 256; k++) a += xs[k] * Wqkv[k * 768 + col];
        float* outp = half ? kwin : qwin;
        outp[bp * 256 + c] = a + bias[col];
    }
}

// ---------------------------------------------------------------------------
// K2: merged launch — route (blocks 0..195) | lepe (blocks 196..1763)  [R8]
// ---------------------------------------------------------------------------
__global__ __launch_bounds__(256) void k_main2(
    const float* __restrict__ qwin, const float* __restrict__ kwin,
    int* __restrict__ ridx,
    const unsigned short* __restrict__ QKV,
    const float* __restrict__ lw, const float* __restrict__ lb,
    unsigned short* __restrict__ Olepe)
{
    __shared__ __align__(16) unsigned char sm2[25600];
    const int t = threadIdx.x;
    const int blk = blockIdx.x;
    if (blk < 196) {
        float* part = (float*)sm2;                // [49][4]
        float* lg   = (float*)(sm2 + 49 * 4 * 4); // [49]
        const int b = blk / 49, p = blk % 49;
        if (t < 196) {
            int d = t >> 2, pr = t & 3;
            const float* qp = &qwin[(b * 49 + p) * 256];
            const float* kp = &kwin[(b * 49 + d) * 256];
            float a = 0.f;
            for (int ch = pr * 64; ch < pr * 64 + 64; ch++) a += qp[ch] * kp[ch];
            part[d * 4 + pr] = a;
        }
        __syncthreads();
        if (t < 49) lg[t] = part[t * 4 + 0] + part[t * 4 + 1] + part[t * 4 + 2] + part[t * 4 + 3];
        __syncthreads();
        if (t == 0) {
            unsigned long long used = 0ull;
            for (int sel = 0; sel < 4; sel++) {
                float best = -1e30f; int bi = 0;
                for (int qq = 0; qq < 49; qq++)
                    if (!((used >> qq) & 1ull) && lg[qq] > best) { best = lg[qq]; bi = qq; }
                used |= (1ull << bi);
                ridx[blk * 4 + sel] = bi;
            }
        }
    } else {
        float* lws = (float*)sm2;                 // [25*256]
        #pragma unroll
        for (int i = 0; i < 25; i++) lws[i * 256 + t] = lw[i * 256 + t];

        const int pl = t & 7;
        const int cg = t >> 3;
        const int c0 = cg * 8;
        const int gid = (blk - 196) * 8 + pl;
        const int b = gid / 3136, rem = gid % 3136;
        const int y = rem / 56, x = rem % 56;
        __syncthreads();

        float acc[8];
        {
            float4 b0 = *reinterpret_cast<const float4*>(lb + c0);
            float4 b1 = *reinterpret_cast<const float4*>(lb + c0 + 4);
            acc[0] = b0.x; acc[1] = b0.y; acc[2] = b0.z; acc[3] = b0.w;
            acc[4] = b1.x; acc[5] = b1.y; acc[6] = b1.z; acc[7] = b1.w;
        }
        #pragma unroll
        for (int ky = 0; ky < 5; ky++) {
            int yy = y + ky - 2;
            if (yy < 0 || yy >= 56) continue;
            #pragma unroll
            for (int kx = 0; kx < 5; kx++) {
                int xx = x + kx - 2;
                if (xx < 0 || xx >= 56) continue;
                bf16x8 v = *reinterpret_cast<const bf16x8*>(
                    QKV + (((b * 56) + yy) * 56 + xx) * 768 + 512 + c0);
                const float* wrow = &lws[(ky * 5 + kx) * 256 + c0];
                float4 w0 = *reinterpret_cast<const float4*>(wrow);
                float4 w1 = *reinterpret_cast<const float4*>(wrow + 4);
                acc[0] += bf2f((unsigned short)v[0]) * w0.x;
                acc[1] += bf2f((unsigned short)v[1]) * w0.y;
                acc[2] += bf2f((unsigned short)v[2]) * w0.z;
                acc[3] += bf2f((unsigned short)v[3]) * w0.w;
                acc[4] += bf2f((unsigned short)v[4]) * w1.x;
                acc[5] += bf2f((unsigned short)v[5]) * w1.y;
                acc[6] += bf2f((unsigned short)v[6]) * w1.z;
                acc[7] += bf2f((unsigned short)v[7]) * w1.w;
            }
        }
        bf16x8 o;
        #pragma unroll
        for (int j = 0; j < 8; j++) o[j] = (short)f2bf(acc[j]);
        *reinterpret_cast<bf16x8*>(Olepe + (size_t)gid * 256 + c0) = o;
    }
}

// ---------------------------------------------------------------------------
// K3: MFMA gathered window attention + "+lepe" add -> Osum.
//     NEW: 37376 B LDS (4 blocks/CU). Q/K staged by global_load_lds with
//     source-XOR (unpadded [row][32]); P buffer split in two 128-key halves.
// ---------------------------------------------------------------------------
__global__ __launch_bounds__(256) void k_attn(
    const unsigned short* __restrict__ QKV,
    const int* __restrict__ ridx,
    const unsigned short* __restrict__ Olepe,
    unsigned short* __restrict__ Osum)
{
    __shared__ __align__(16) unsigned char smem[37376];
    unsigned short* Vt = (unsigned short*)smem;                  // [32][264] = 16896 B
    unsigned short* Qs = (unsigned short*)(smem + 16896);        // [64][32]  =  4096 B
    unsigned short* Ks = (unsigned short*)(smem + 20992);        // [256][32] = 16384 B
    unsigned short* Ps = (unsigned short*)(smem + 16896);        // 4 x [16][136] = 17408 B (union Qs/Ks)

    const int p = blockIdx.x, head = blockIdx.y, b = blockIdx.z;
    const int t = threadIdx.x;
    const int wi = p / 7, wj = p % 7;
    const int wave = t >> 6, lane = t & 63, quad = lane >> 4, lo = lane & 15;
    const int pix4 = t >> 2, c4 = t & 3;

    // ---- Q stage: DMA, LDS slot (pix,c4) holds global chunk c4^((pix>>1)&3) ----
    {
        int y = wi * 8 + (pix4 >> 3), x = wj * 8 + (pix4 & 7);
        int e = c4 ^ ((pix4 >> 1) & 3);
        load_lds16(QKV + (size_t)(((b * 56) + y) * 56 + x) * 768 + head * 32 + e * 8,
                   &Qs[pix4 * 32 + c4 * 8]);
    }
    // ---- K stage: DMA (same scheme); V transposed via scalar stores ----
    #pragma unroll
    for (int pass = 0; pass < 4; pass++) {
        int sel = ridx[(b * 49 + p) * 4 + pass];
        int si = sel / 7, sj = sel % 7;
        int y = si * 8 + (pix4 >> 3), x = sj * 8 + (pix4 & 7);
        const unsigned short* base = QKV + (size_t)(((b * 56) + y) * 56 + x) * 768 + 256 + head * 32;
        int krow = pass * 64 + pix4;
        int e = c4 ^ ((krow >> 1) & 3);
        load_lds16(base + e * 8, &Ks[krow * 32 + c4 * 8]);
        bf16x8 vv = *reinterpret_cast<const bf16x8*>(base + 256 + c4 * 8);
        #pragma unroll
        for (int j = 0; j < 8; j++)
            Vt[(c4 * 8 + j) * 264 + krow] = (unsigned short)vv[j];
    }
    __syncthreads();   // drains DMA (vmcnt) + ds stores

    // ---- QK^T ----
    f32x4 sc[16];
    {
        int row = wave * 16 + lo;
        bf16x8 af = *reinterpret_cast<const bf16x8*>(
            &Qs[row * 32 + ((quad ^ ((row >> 1) & 3)) * 8)]);
        f32x4 z = (f32x4){0.f, 0.f, 0.f, 0.f};
        #pragma unroll
        for (int nt = 0; nt < 16; nt++) {
            int key = nt * 16 + lo;
            bf16x8 bfr = *reinterpret_cast<const bf16x8*>(
                &Ks[key * 32 + ((quad ^ ((key >> 1) & 3)) * 8)]);
            sc[nt] = __builtin_amdgcn_mfma_f32_16x16x32_bf16(af, bfr, z, 0, 0, 0);
        }
    }
    // ---- softmax over 256 keys ----
    float M[4] = {-1e30f, -1e30f, -1e30f, -1e30f};
    #pragma unroll
    for (int nt = 0; nt < 16; nt++)
        #pragma unroll
        for (int r = 0; r < 4; r++) M[r] = fmaxf(M[r], sc[nt][r] * 0.0625f);
    #pragma unroll
    for (int d = 1; d < 16; d <<= 1)
        #pragma unroll
        for (int r = 0; r < 4; r++) M[r] = fmaxf(M[r], __shfl_xor(M[r], d));
    float l[4] = {0.f, 0.f, 0.f, 0.f};
    #pragma unroll
    for (int nt = 0; nt < 16; nt++)
        #pragma unroll
        for (int r = 0; r < 4; r++) {
            float e = __expf(sc[nt][r] * 0.0625f - M[r]);
            sc[nt][r] = e;
            l[r] += e;
        }
    #pragma unroll
    for (int d = 1; d < 16; d <<= 1)
        #pragma unroll
        for (int r = 0; r < 4; r++) l[r] += __shfl_xor(l[r], d);

    __syncthreads();   // Qs/Ks dead -> Ps region writable

    unsigned short* myPs = Ps + wave * 16 * 136;
    f32x4 o0 = (f32x4){0.f, 0.f, 0.f, 0.f}, o1 = o0;

    // ---- P half 0 (keys 0..127) + PV kt 0..3 ----
    #pragma unroll
    for (int nt = 0; nt < 8; nt++)
        #pragma unroll
        for (int r = 0; r < 4; r++)
            myPs[(quad * 4 + r) * 136 + nt * 16 + lo] = f2bf(sc[nt][r]);
    #pragma unroll
    for (int kt = 0; kt < 4; kt++) {
        bf16x8 pa = *reinterpret_cast<const bf16x8*>(
            &myPs[lo * 136 + kt * 32 + quad * 8]);
        bf16x8 vb0 = *reinterpret_cast<const bf16x8*>(
            &Vt[lo * 264 + kt * 32 + quad * 8]);
        bf16x8 vb1 = *reinterpret_cast<const bf16x8*>(
            &Vt[(16 + lo) * 264 + kt * 32 + quad * 8]);
        o0 = __builtin_amdgcn_mfma_f32_16x16x32_bf16(pa, vb0, o0, 0, 0, 0);
        o1 = __builtin_amdgcn_mfma_f32_16x16x32_bf16(pa, vb1, o1, 0, 0, 0);
    }
    __syncthreads();   // WAR guard before overwriting P half

    // ---- P half 1 (keys 128..255) + PV kt 4..7 ----
    #pragma unroll
    for (int nt = 8; nt < 16; nt++)
        #pragma unroll
        for (int r = 0; r < 4; r++)
            myPs[(quad * 4 + r) * 136 + (nt - 8) * 16 + lo] = f2bf(sc[nt][r]);
    #pragma unroll
    for (int kt = 4; kt < 8; kt++) {
        bf16x8 pa = *reinterpret_cast<const bf16x8*>(
            &myPs[lo * 136 + (kt - 4) * 32 + quad * 8]);
        bf16x8 vb0 = *reinterpret_cast<const bf16x8*>(
            &Vt[lo * 264 + kt * 32 + quad * 8]);
        bf16x8 vb1 = *reinterpret_cast<const bf16x8*>(
            &Vt[(16 + lo) * 264 + kt * 32 + quad * 8]);
        o0 = __builtin_amdgcn_mfma_f32_16x16x32_bf16(pa, vb0, o0, 0, 0, 0);
        o1 = __builtin_amdgcn_mfma_f32_16x16x32_bf16(pa, vb1, o1, 0, 0, 0);
    }

    // ---- epilogue: /L, +lepe, store ----
    #pragma unroll
    for (int r = 0; r < 4; r++) {
        int q = wave * 16 + quad * 4 + r;
        int y = wi * 8 + (q >> 3), x = wj * 8 + (q & 7);
        size_t base = (size_t)(((b * 56) + y) * 56 + x) * 256 + head * 32;
        const unsigned short* lp = Olepe + base;
        unsigned short* op = Osum + base;
        float inv = 1.0f / l[r];
        op[lo]      = f2bf(o0[r] * inv + bf2f(lp[lo]));
        op[16 + lo] = f2bf(o1[r] * inv + bf2f(lp[16 + lo]));
    }
}

// ---------------------------------------------------------------------------
// K4: out proj (MFMA): Osum[12544,256] @ Wo[256,256] + bo -> fp32 out  [R8]
// ---------------------------------------------------------------------------
__global__ __launch_bounds__(256) void k_proj(
    const unsigned short* __restrict__ A,
    const unsigned short* __restrict__ Bt,   // Wto [256][256]
    const float* __restrict__ bias,
    float* __restrict__ O)
{
    __shared__ unsigned short As[128 * 32];
    __shared__ unsigned short Bs[64 * 32];
    const int t = threadIdx.x;
    const int m0 = blockIdx.x * 128, n0 = blockIdx.y * 64;
    const int wave = t >> 6, lane = t & 63, quad = lane >> 4, lo = lane & 15;
    const int sr = wave * 16 + (lane >> 2);
    const int sc = lane & 3;
    f32x4 acc[2][4];
    #pragma unroll
    for (int i = 0; i < 2; i++)
        #pragma unroll
        for (int j = 0; j < 4; j++) acc[i][j] = (f32x4){0.f, 0.f, 0.f, 0.f};

    for (int kt = 0; kt < 256; kt += 32) {
        __syncthreads();
        #pragma unroll
        for (int j = 0; j < 2; j++) {
            int row = j * 64 + sr;
            int e = sc ^ ((row >> 1) & 3);
            load_lds16(A + (size_t)(m0 + row) * 256 + kt + e * 8, &As[row * 32 + sc * 8]);
        }
        {
            int e = sc ^ ((sr >> 1) & 3);
            load_lds16(Bt + (size_t)(n0 + sr) * 256 + kt + e * 8, &Bs[sr * 32 + sc * 8]);
        }
        __syncthreads();
        bf16x8 af[2], bfr[4];
        #pragma unroll
        for (int mt = 0; mt < 2; mt++) {
            int row = wave * 32 + mt * 16 + lo;
            int c = quad ^ ((row >> 1) & 3);
            af[mt] = *reinterpret_cast<const bf16x8*>(&As[row * 32 + c * 8]);
        }
        #pragma unroll
        for (int nt = 0; nt < 4; nt++) {
            int col = nt * 16 + lo;
            int c = quad ^ ((col >> 1) & 3);
            bfr[nt] = *reinterpret_cast<const bf16x8*>(&Bs[col * 32 + c * 8]);
        }
        #pragma unroll
        for (int mt = 0; mt < 2; mt++)
            #pragma unroll
            for (int nt = 0; nt < 4; nt++)
                acc[mt][nt] = __builtin_amdgcn_mfma_f32_16x16x32_bf16(
                    af[mt], bfr[nt], acc[mt][nt], 0, 0, 0);
    }
    float bv[4];
    #pragma unroll
    for (int nt = 0; nt < 4; nt++) bv[nt] = bias[n0 + nt * 16 + lo];
    #pragma unroll
    for (int mt = 0; mt < 2; mt++)
        #pragma unroll
        for (int nt = 0; nt < 4; nt++) {
            int n = n0 + nt * 16 + lo;
            #pragma unroll
            for (int r = 0; r < 4; r++) {
                int m = m0 + wave * 32 + mt * 16 + quad * 4 + r;
                O[m * 256 + n] = acc[mt][nt][r] + bv[nt];
            }
        }
}

// ---------------------------------------------------------------------------
extern "C" void kernel_launch(void* const* d_in, const int* in_sizes, int n_in,
                              void* d_out, int out_size, void* d_ws, size_t ws_size,
                              hipStream_t stream)
{
    const float* x    = (const float*)d_in[0];
    const float* Wqkv = (const float*)d_in[1];
    const float* bqkv = (const float*)d_in[2];
    const float* Wo   = (const float*)d_in[3];
    const float* bo   = (const float*)d_in[4];
    const float* lw   = (const float*)d_in[5];
    const float* lb   = (const float*)d_in[6];
    float* out = (float*)d_out;

    char* ws = (char*)d_ws;
    size_t off = 0;
    unsigned short* qkv   = (unsigned short*)(ws + off); off += (size_t)NPIX * 768 * 2;
    unsigned short* xb    = (unsigned short*)(ws + off); off += (size_t)NPIX * 256 * 2;
    unsigned short* Wtq   = (unsigned short*)(ws + off); off += 768 * 256 * 2;
    unsigned short* Wto   = (unsigned short*)(ws + off); off += 256 * 256 * 2;
    unsigned short* Osum  = (unsigned short*)(ws + off); off += (size_t)NPIX * 256 * 2;
    unsigned short* Olepe = (unsigned short*)(ws + off); off += (size_t)NPIX * 256 * 2;
    float* xmean = (float*)(ws + off); off += 196 * 256 * 4;
    float* qwin  = (float*)(ws + off); off += 196 * 256 * 4;
    float* kwin  = (float*)(ws + off); off += 196 * 256 * 4;
    int*   ridx  = (int*)(ws + off);   off += 196 * 4 * 4;

    k_prep <<<dim3(456),      256, 0, stream>>>(x, xb, xmean, Wqkv, Wo, Wtq, Wto);
    k_main1<<<dim3(980),      256, 0, stream>>>(xb, Wtq, bqkv, qkv, xmean, Wqkv, qwin, kwin);
    k_main2<<<dim3(1764),     256, 0, stream>>>(qwin, kwin, ridx, qkv, lw, lb, Olepe);
    k_attn <<<dim3(49, 8, 4), 256, 0, stream>>>(qkv, ridx, Olepe, Osum);
    k_proj <<<dim3(98, 4),    256, 0, stream>>>(Osum, Wto, bo, out);
}